// Round 13
// baseline (2133.262 us; speedup 1.0000x reference)
//
#include <hip/hip_runtime.h>
#include <math.h>

#pragma clang fp contract(off)   // no implicit fusion; FMA only where ref has it

// Problem constants (fixed by the reference)
#define BB   8
#define NN   16384
#define FF   32
#define SS   2048
#define KK   32
#define OUTC 128

typedef float v2f __attribute__((ext_vector_type(2)));

// force a value into uniform (SGPR) representation
__device__ __forceinline__ float uni(float v) {
    return __uint_as_float(__builtin_amdgcn_readfirstlane(__float_as_uint(v)));
}

__device__ __forceinline__ v2f splat2(float s) { v2f r; r.x = s; r.y = s; return r; }

// prefix popcount of 64-bit ballot below this lane (2 VALU ops)
__device__ __forceinline__ int mbcnt64(unsigned long long m) {
    return __builtin_amdgcn_mbcnt_hi((unsigned)(m >> 32),
           __builtin_amdgcn_mbcnt_lo((unsigned)m, 0));
}

// ---------------------------------------------------------------------------
// Reference-bit-exact fp32 helpers (validated R0-R7):
// x_sq / s_sq: numpy pairwise_sum scalar 8-accumulator block (n=32, no FMA)
__device__ __forceinline__ float np_sumsq32(const float* a) {
    float r[8];
#pragma unroll
    for (int j = 0; j < 8; j++) r[j] = a[j] * a[j];
#pragma unroll
    for (int t = 1; t < 4; t++) {
#pragma unroll
        for (int j = 0; j < 8; j++) {
            float e = a[8 * t + j] * a[8 * t + j];
            r[j] = r[j] + e;
        }
    }
    return ((r[0] + r[1]) + (r[2] + r[3])) + ((r[4] + r[5]) + (r[6] + r[7]));
}

// ---------------------------------------------------------------------------
// K1a: x_sq[b,n] = ref-order sum_f x^2
__global__ __launch_bounds__(256) void xsq_kernel(const float* __restrict__ x,
                                                  float* __restrict__ xsq) {
    int gid = blockIdx.x * 256 + threadIdx.x;      // < B*N
    const float4* r = (const float4*)(x + (size_t)gid * FF);
    float a[32];
#pragma unroll
    for (int j = 0; j < 8; j++) {
        float4 v = r[j];
        a[4 * j] = v.x; a[4 * j + 1] = v.y; a[4 * j + 2] = v.z; a[4 * j + 3] = v.w;
    }
    xsq[gid] = np_sumsq32(a);
}

// ---------------------------------------------------------------------------
// K1b: gather sampled features (row-major [B,S,F]) + ref-order s_sq
__global__ __launch_bounds__(256) void gather_kernel(const float* __restrict__ x,
                                                     const int* __restrict__ sidx,
                                                     float* __restrict__ sampled,
                                                     float* __restrict__ ssq) {
    int gid = blockIdx.x * 256 + threadIdx.x;      // < B*S
    int b = gid >> 11;
    int idx = sidx[gid];
    const float4* r = (const float4*)(x + ((size_t)b * NN + idx) * FF);
    float4* wo = (float4*)(sampled + (size_t)gid * FF);
    float a[32];
#pragma unroll
    for (int j = 0; j < 8; j++) {
        float4 v = r[j];
        a[4 * j] = v.x; a[4 * j + 1] = v.y; a[4 * j + 2] = v.z; a[4 * j + 3] = v.w;
        wo[j] = v;
    }
    ssq[gid] = np_sumsq32(a);
}

// ---------------------------------------------------------------------------
// K1c: sampled [B,S,F] -> output sampled_batch [B,F,S] (transpose via LDS)
__global__ __launch_bounds__(256) void transpose_kernel(const float* __restrict__ sampled,
                                                        float* __restrict__ out_samp) {
    __shared__ float tile[32][65];
    int b = blockIdx.x >> 5, sg = blockIdx.x & 31;
    int s0 = sg * 64;
    int tid = threadIdx.x;
    int f = tid & 31, si = tid >> 5;               // si in 0..7
#pragma unroll
    for (int r = 0; r < 8; r++) {
        int s = r * 8 + si;
        tile[f][s] = sampled[((size_t)b * SS + s0 + s) * FF + f];
    }
    __syncthreads();
#pragma unroll
    for (int r = 0; r < 8; r++) {
        int flat = r * 256 + tid;
        int fo = flat >> 6, sw = flat & 63;
        out_samp[((size_t)b * FF + fo) * SS + s0 + sw] = tile[fo][sw];
    }
}

// ---------------------------------------------------------------------------
// K1d v2: x [B,N,F] -> float4-PACKED blocked transpose
// xt[b][t][j][l] (float4), j = f/4, l = lane: point n = t*64+l's features
// 4j..4j+3 sit contiguously at ((t*8+j)*64 + l)*16B. topk lane loads ONE
// global_load_dwordx4 per j: 64 lanes x 16B = 1024B fully coalesced.
__global__ __launch_bounds__(256) void transpose_x_kernel(const float* __restrict__ x,
                                                          float* __restrict__ xt) {
    __shared__ float tile[32][65];
    int b = blockIdx.x >> 8;                // B*256 blocks
    int tg = blockIdx.x & 255;              // tile index t
    int n0 = tg * 64;
    int tid = threadIdx.x;
    int f = tid & 31, si = tid >> 5;        // si in 0..7
#pragma unroll
    for (int r = 0; r < 8; r++) {
        int n = r * 8 + si;
        tile[f][n] = x[((size_t)b * NN + n0 + n) * FF + f];
    }
    __syncthreads();
    float* wo = xt + (((size_t)b * 256 + tg) * 2048);   // 2048 floats/tile
#pragma unroll
    for (int r = 0; r < 8; r++) {
        int flat = r * 256 + tid;           // = j*256 + l*4 + e  (j = r)
        int e = flat & 3, l = (flat >> 2) & 63;
        wo[flat] = tile[4 * r + e][l];
    }
}

// ---------------------------------------------------------------------------
// K2: per-point MLP, h2[b,n,:] = W2 @ relu(W1 @ x + b1) + b2  (fp32, VALU)
__global__ __launch_bounds__(256) void mlp_kernel(const float* __restrict__ x,
                                                  const float* __restrict__ W1,
                                                  const float* __restrict__ b1,
                                                  const float* __restrict__ W2,
                                                  const float* __restrict__ b2,
                                                  float* __restrict__ h2) {
    __shared__ float xs[64][36];          // padded
    __shared__ float hs[8512];            // h1t [128][65] then reused as h2s [64][133]
    int tid = threadIdx.x, lane = tid & 63;
    int wu = __builtin_amdgcn_readfirstlane(tid >> 6);
    size_t p0 = (size_t)blockIdx.x * 64;

    for (int i = tid; i < 64 * 8; i += 256) {
        int row = i >> 3, seg = i & 7;
        *(float4*)&xs[row][seg * 4] = *(const float4*)(x + (p0 + row) * FF + seg * 4);
    }
    __syncthreads();

    float xr[32];
    {
        const float4* r = (const float4*)&xs[lane][0];
#pragma unroll
        for (int j = 0; j < 8; j++) {
            float4 v = r[j];
            xr[4 * j] = v.x; xr[4 * j + 1] = v.y; xr[4 * j + 2] = v.z; xr[4 * j + 3] = v.w;
        }
    }
#pragma unroll 4
    for (int i = 0; i < 32; i++) {
        int o = wu * 32 + i;
        const float4* wr = (const float4*)(W1 + o * FF);
        float a = b1[o];
#pragma unroll
        for (int j = 0; j < 8; j++) {
            float4 v = wr[j];
            a = fmaf(v.x, xr[4 * j], a);     a = fmaf(v.y, xr[4 * j + 1], a);
            a = fmaf(v.z, xr[4 * j + 2], a); a = fmaf(v.w, xr[4 * j + 3], a);
        }
        hs[o * 65 + lane] = fmaxf(a, 0.f);
    }
    __syncthreads();
    float acc[32];
#pragma unroll
    for (int i = 0; i < 32; i++) acc[i] = b2[wu * 32 + i];
    for (int k4 = 0; k4 < 32; k4++) {
        float h0 = hs[(4 * k4 + 0) * 65 + lane];
        float h1v = hs[(4 * k4 + 1) * 65 + lane];
        float h2v = hs[(4 * k4 + 2) * 65 + lane];
        float h3v = hs[(4 * k4 + 3) * 65 + lane];
#pragma unroll
        for (int i = 0; i < 32; i++) {
            const float4 v = *(const float4*)(W2 + (wu * 32 + i) * OUTC + 4 * k4);
            acc[i] = fmaf(v.x, h0, acc[i]);  acc[i] = fmaf(v.y, h1v, acc[i]);
            acc[i] = fmaf(v.z, h2v, acc[i]); acc[i] = fmaf(v.w, h3v, acc[i]);
        }
    }
    __syncthreads();
#pragma unroll 4
    for (int i = 0; i < 32; i++) hs[lane * 133 + wu * 32 + i] = acc[i];
    __syncthreads();
    for (int j = 0; j < 32; j++) {
        int flat = j * 256 + tid;
        int p = flat >> 7, o = flat & 127;
        h2[(p0 + p) * OUTC + o] = hs[p * 133 + o];
    }
}

// ---------------------------------------------------------------------------
// K3 v15: 4 queries/wave — q0,q1 in SGPRs (as R8), q2,q3 in LDS read as
// per-tile BROADCAST ds_read_b64 (uniform address, conflict-free).
// R12 post-mortem: lockstep barrier REGRESSED (645->775; lds_pad was DCE'd
// so the occupancy pin never applied; cross-block L1 thrash defeats
// intra-block sharing; barrier coupling cost ~130us). Reverted.
// R9/R11: qpB in VGPRs spills (64-reg array + compact temps > 128 cap);
// SGPRs are architecturally capped ~102 -> no more SGPR queries.
// v15 rebalances pipes instead: R8's LDS pipe is IDLE in the distance
// loop. Halve VMEM bytes (17.2 -> 8.6 GB; the R8 wall was 26.6 of ~34.5
// TB/s L2) by doubling queries/wave, and put the extra query-operand
// traffic on LDS broadcast (~190 cyc/wave-tile on the idle pipe).
// LICM guard: opaque-zero VGPR from per-iteration asm volatile in the
// qlds address prevents the compiler hoisting 32 loop-invariant LDS
// reads back into 64 registers (which would reintroduce the spill).
// Diagnostics: success = dur ~430-520, VGPR 70-90, WRITE_SIZE 2048 KB.
__device__ __forceinline__ bool lessp(float da, int ia, float db, int ib) {
    return da < db || (da == db && ia < ib);
}
__device__ __forceinline__ void cswap(float& d, int& i, int j, bool dirAsc, int lane) {
    float od = __shfl_xor(d, j);
    int   oi = __shfl_xor(i, j);
    bool lower = (lane & j) == 0;
    bool oLess = lessp(od, oi, d, i);
    if (oLess == (lower == dirAsc)) { d = od; i = oi; }
}
__device__ __forceinline__ void sort64(float& d, int& i, bool asc, int lane) {
#pragma unroll
    for (int k = 2; k <= 64; k <<= 1) {
        bool ba = (((lane & k) == 0) == asc);
#pragma unroll
        for (int j = k >> 1; j > 0; j >>= 1) cswap(d, i, j, ba, lane);
    }
}
// sort m valid slots, keep lowest-64 lex-sorted in [0,64); return 32nd-smallest
__device__ __forceinline__ float wave_compact2(float* bd, int* bi, int m, int lane) {
    float d0 = (lane < m) ? bd[lane] : INFINITY;
    int   i0 = (lane < m) ? bi[lane] : 0x7fffffff;
    float d1 = (lane + 64 < m) ? bd[lane + 64] : INFINITY;
    int   i1 = (lane + 64 < m) ? bi[lane + 64] : 0x7fffffff;
    sort64(d0, i0, true, lane);
    sort64(d1, i1, false, lane);
    bool t = lessp(d1, i1, d0, i0);
    float ld = t ? d1 : d0;
    int   li = t ? i1 : i0;
#pragma unroll
    for (int j = 32; j > 0; j >>= 1) cswap(ld, li, j, true, lane);
    bd[lane] = ld; bi[lane] = li;
    return uni(__shfl(ld, 31));            // uniform across wave
}

__device__ __forceinline__ void insert_cand(float dv, int n, int lane,
                                            float* bd, int* bi, int& cnt, float& tau) {
    unsigned long long m = __ballot(dv < tau);
    if (m) {
        int pos = cnt + mbcnt64(m);
        if (dv < tau) { bd[pos] = dv; bi[pos] = n; }
        cnt += __builtin_popcountll(m);
        if (cnt > 64) { tau = wave_compact2(bd, bi, cnt, lane); cnt = 32; }
    }
}

__global__ __launch_bounds__(256, 4) void topk_kernel(const float* __restrict__ xt,
                                                      const float* __restrict__ x_sq,
                                                      const float* __restrict__ sampled,
                                                      const float* __restrict__ s_sq,
                                                      int* __restrict__ nbr) {
    int b = blockIdx.x & 7;                 // XCD-by-batch swizzle
    int qg = blockIdx.x >> 3;               // 0..127
    int tid = threadIdx.x, lane = tid & 63;
    int w = __builtin_amdgcn_readfirstlane(tid >> 6);
    __shared__ float bufd[16][128];
    __shared__ int   bufi[16][128];
    __shared__ v2f   qlds[4][32];           // per-wave q2,q3 pairs (256 B/wave)
    int s0 = qg * 16;                       // 16 queries per block, 4 per wave
    const float* xtb = xt + (size_t)b * (NN * FF);   // packed [256][8][64]f4
    const float* xqb = x_sq + (size_t)b * NN;

    // q0,q1 packed {q0,q1} -> wave-uniform SGPR pairs (as R8)
    v2f qp[32];
    {
        const float* sp0 = sampled + ((size_t)b * SS + s0 + w * 4 + 0) * FF;
        const float* sp1 = sampled + ((size_t)b * SS + s0 + w * 4 + 1) * FF;
#pragma unroll
        for (int k = 0; k < 32; k++) {
            qp[k].x = uni(sp0[k]);
            qp[k].y = uni(sp1[k]);
        }
    }
    // q2,q3 -> LDS (same-wave write/read; no barrier needed)
    {
        const float* sp2 = sampled + ((size_t)b * SS + s0 + w * 4 + 2) * FF;
        const float* sp3 = sampled + ((size_t)b * SS + s0 + w * 4 + 3) * FF;
        if (lane < 32) {
            v2f q; q.x = sp2[lane]; q.y = sp3[lane];
            qlds[w][lane] = q;
        }
    }
    v2f ssqA, ssqB;
    ssqA.x = uni(s_sq[b * SS + s0 + w * 4 + 0]);
    ssqA.y = uni(s_sq[b * SS + s0 + w * 4 + 1]);
    ssqB.x = s_sq[b * SS + s0 + w * 4 + 2];
    ssqB.y = s_sq[b * SS + s0 + w * 4 + 3];

    float* bq0d = &bufd[w * 4 + 0][0];  int* bq0i = &bufi[w * 4 + 0][0];
    float* bq1d = &bufd[w * 4 + 1][0];  int* bq1i = &bufi[w * 4 + 1][0];
    float* bq2d = &bufd[w * 4 + 2][0];  int* bq2i = &bufi[w * 4 + 2][0];
    float* bq3d = &bufd[w * 4 + 3][0];  int* bq3i = &bufi[w * 4 + 3][0];
    int   cnt0 = 0, cnt1 = 0, cnt2 = 0, cnt3 = 0;   // wave-uniform
    float tau0 = INFINITY, tau1 = INFINITY, tau2 = INFINITY, tau3 = INFINITY;

    const v2f* qw = &qlds[w][0];
    float xqv = xqb[lane];

    for (int t = 0; t < NN / 64; t++) {
        // opaque zero (per-iteration volatile asm): makes the qlds read
        // addresses loop-variant so LICM cannot hoist 32 LDS reads into
        // 64 registers (the R9/R11 spill would return).
        int zot;
        asm volatile("v_mov_b32 %0, 0" : "=v"(zot));
        // lane handles point n = t*64+lane; 8 coalesced dwordx4 loads at
        // imm offsets j*1024B from a single per-lane float4 base.
        const float4* pn = (const float4*)(xtb + (size_t)t * 2048) + lane;
        float4 vv[8];
#pragma unroll
        for (int j = 0; j < 8; j++) vv[j] = pn[j * 64];
        float xq_c = xqv;
        v2f cA; cA.x = 0.f; cA.y = 0.f;
        v2f cB; cB.x = 0.f; cB.y = 0.f;
#pragma unroll
        for (int j = 0; j < 8; j++) {
            float4 v = vv[j];
            // each half is the ref-exact sequential FMA order f=0..31
            cA = __builtin_elementwise_fma(qp[4 * j + 0], splat2(v.x), cA);
            cB = __builtin_elementwise_fma(qw[4 * j + 0 + zot], splat2(v.x), cB);
            cA = __builtin_elementwise_fma(qp[4 * j + 1], splat2(v.y), cA);
            cB = __builtin_elementwise_fma(qw[4 * j + 1 + zot], splat2(v.y), cB);
            cA = __builtin_elementwise_fma(qp[4 * j + 2], splat2(v.z), cA);
            cB = __builtin_elementwise_fma(qw[4 * j + 2 + zot], splat2(v.z), cB);
            cA = __builtin_elementwise_fma(qp[4 * j + 3], splat2(v.w), cA);
            cB = __builtin_elementwise_fma(qw[4 * j + 3 + zot], splat2(v.w), cB);
        }
        if (t + 1 < NN / 64) xqv = xqb[(t + 1) * 64 + lane];

        // ref combine order per half: (ssq + xq) - (c + c)
        v2f dA = (ssqA + splat2(xq_c)) - (cA + cA);
        v2f dB = (ssqB + splat2(xq_c)) - (cB + cB);
        int n = t * 64 + lane;
        insert_cand(dA.x, n, lane, bq0d, bq0i, cnt0, tau0);
        insert_cand(dA.y, n, lane, bq1d, bq1i, cnt1, tau1);
        insert_cand(dB.x, n, lane, bq2d, bq2i, cnt2, tau2);
        insert_cand(dB.y, n, lane, bq3d, bq3i, cnt3, tau3);
    }
    // final: compact (lex-sorts survivors) and emit first 32 per query
    wave_compact2(bq0d, bq0i, cnt0, lane);
    wave_compact2(bq1d, bq1i, cnt1, lane);
    wave_compact2(bq2d, bq2i, cnt2, lane);
    wave_compact2(bq3d, bq3i, cnt3, lane);
    int s = s0 + w * 4;
    if (lane < 32) {
        nbr[((size_t)b * SS + s) * KK + lane]     = bq0i[lane];
        nbr[((size_t)b * SS + s + 1) * KK + lane] = bq1i[lane];
        nbr[((size_t)b * SS + s + 2) * KK + lane] = bq2i[lane];
        nbr[((size_t)b * SS + s + 3) * KK + lane] = bq3i[lane];
    }
}

// ---------------------------------------------------------------------------
// K4: features_batch[b,o,s] = max_k h2[b, nbr[b,s,k], o]; block=128, 16 s/block
__global__ __launch_bounds__(128) void maxgather_kernel(const float* __restrict__ h2,
                                                        const int* __restrict__ nbr,
                                                        float* __restrict__ out_feat) {
    __shared__ float fs[128][17];
    int b = blockIdx.x & 7;
    int sg = blockIdx.x >> 3;               // 0..127
    int s0 = sg * 16;
    int tid = threadIdx.x;                  // o = tid (0..127)
    for (int si = 0; si < 16; si++) {
        int s = s0 + si;
        const int* row = nbr + ((size_t)b * SS + s) * KK;
        float m = -INFINITY;
#pragma unroll 4
        for (int k = 0; k < KK; k++) {
            int idx = row[k];
            float v = h2[((size_t)b * NN + idx) * OUTC + tid];
            m = fmaxf(m, v);
        }
        fs[tid][si] = m;
    }
    __syncthreads();
#pragma unroll
    for (int j = 0; j < 16; j++) {
        int flat = j * 128 + tid;
        int fo = flat >> 4, sw = flat & 15;
        out_feat[((size_t)b * OUTC + fo) * SS + s0 + sw] = fs[fo][sw];
    }
}

// ---------------------------------------------------------------------------
extern "C" void kernel_launch(void* const* d_in, const int* in_sizes, int n_in,
                              void* d_out, int out_size, void* d_ws, size_t ws_size,
                              hipStream_t stream) {
    const float* x    = (const float*)d_in[0];
    const int*   sidx = (const int*)d_in[1];
    const float* W1   = (const float*)d_in[2];
    const float* b1   = (const float*)d_in[3];
    const float* W2   = (const float*)d_in[4];
    const float* b2   = (const float*)d_in[5];

    float* out_feat = (float*)d_out;                       // [B,128,S]
    float* out_samp = out_feat + (size_t)BB * OUTC * SS;   // [B,32,S]

    float* h2      = (float*)d_ws;                         // B*N*128 fp32 = 64 MB
    float* sampled = h2 + (size_t)BB * NN * OUTC;          // B*S*F
    float* xsq     = sampled + (size_t)BB * SS * FF;       // B*N
    float* ssq     = xsq + (size_t)BB * NN;                // B*S
    int*   nbr     = (int*)(ssq + (size_t)BB * SS);        // B*S*K
    // xt (16.8 MB) ALIASES the h2 region (64 MB): topk consumes xt strictly
    // before mlp writes h2 (same stream, ordered). No extra workspace.
    float* xt      = h2;

    xsq_kernel<<<dim3(BB * NN / 256), dim3(256), 0, stream>>>(x, xsq);
    gather_kernel<<<dim3(BB * SS / 256), dim3(256), 0, stream>>>(x, sidx, sampled, ssq);
    transpose_kernel<<<dim3(BB * SS / 64), dim3(256), 0, stream>>>(sampled, out_samp);
    transpose_x_kernel<<<dim3(BB * 256), dim3(256), 0, stream>>>(x, xt);
    topk_kernel<<<dim3(BB * SS / 16), dim3(256), 0, stream>>>(xt, xsq, sampled, ssq, nbr);
    mlp_kernel<<<dim3(BB * NN / 64), dim3(256), 0, stream>>>(x, W1, b1, W2, b2, h2);
    maxgather_kernel<<<dim3(BB * SS / 16), dim3(128), 0, stream>>>(h2, nbr, out_feat);
}

// Round 15
// 998.673 us; speedup vs baseline: 2.1361x; 2.1361x over previous
//
#include <hip/hip_runtime.h>
#include <math.h>

#pragma clang fp contract(off)   // no implicit fusion; FMA only where ref has it

// Problem constants (fixed by the reference)
#define BB   8
#define NN   16384
#define FF   32
#define SS   2048
#define KK   32
#define OUTC 128

typedef float v2f __attribute__((ext_vector_type(2)));

// force a value into uniform (SGPR) representation
__device__ __forceinline__ float uni(float v) {
    return __uint_as_float(__builtin_amdgcn_readfirstlane(__float_as_uint(v)));
}

// pin a value into a VGPR (blocks scalarization/remat of the producing load)
__device__ __forceinline__ float vpin(float v) {
    float r;
    asm volatile("v_mov_b32 %0, %1" : "=v"(r) : "v"(v));
    return r;
}

__device__ __forceinline__ v2f splat2(float s) { v2f r; r.x = s; r.y = s; return r; }

// prefix popcount of 64-bit ballot below this lane (2 VALU ops)
__device__ __forceinline__ int mbcnt64(unsigned long long m) {
    return __builtin_amdgcn_mbcnt_hi((unsigned)(m >> 32),
           __builtin_amdgcn_mbcnt_lo((unsigned)m, 0));
}

// ---------------------------------------------------------------------------
// Reference-bit-exact fp32 helpers (validated R0-R7):
// x_sq / s_sq: numpy pairwise_sum scalar 8-accumulator block (n=32, no FMA)
__device__ __forceinline__ float np_sumsq32(const float* a) {
    float r[8];
#pragma unroll
    for (int j = 0; j < 8; j++) r[j] = a[j] * a[j];
#pragma unroll
    for (int t = 1; t < 4; t++) {
#pragma unroll
        for (int j = 0; j < 8; j++) {
            float e = a[8 * t + j] * a[8 * t + j];
            r[j] = r[j] + e;
        }
    }
    return ((r[0] + r[1]) + (r[2] + r[3])) + ((r[4] + r[5]) + (r[6] + r[7]));
}

// ---------------------------------------------------------------------------
// K1a: x_sq[b,n] = ref-order sum_f x^2
__global__ __launch_bounds__(256) void xsq_kernel(const float* __restrict__ x,
                                                  float* __restrict__ xsq) {
    int gid = blockIdx.x * 256 + threadIdx.x;      // < B*N
    const float4* r = (const float4*)(x + (size_t)gid * FF);
    float a[32];
#pragma unroll
    for (int j = 0; j < 8; j++) {
        float4 v = r[j];
        a[4 * j] = v.x; a[4 * j + 1] = v.y; a[4 * j + 2] = v.z; a[4 * j + 3] = v.w;
    }
    xsq[gid] = np_sumsq32(a);
}

// ---------------------------------------------------------------------------
// K1b: gather sampled features (row-major [B,S,F]) + ref-order s_sq
__global__ __launch_bounds__(256) void gather_kernel(const float* __restrict__ x,
                                                     const int* __restrict__ sidx,
                                                     float* __restrict__ sampled,
                                                     float* __restrict__ ssq) {
    int gid = blockIdx.x * 256 + threadIdx.x;      // < B*S
    int b = gid >> 11;
    int idx = sidx[gid];
    const float4* r = (const float4*)(x + ((size_t)b * NN + idx) * FF);
    float4* wo = (float4*)(sampled + (size_t)gid * FF);
    float a[32];
#pragma unroll
    for (int j = 0; j < 8; j++) {
        float4 v = r[j];
        a[4 * j] = v.x; a[4 * j + 1] = v.y; a[4 * j + 2] = v.z; a[4 * j + 3] = v.w;
        wo[j] = v;
    }
    ssq[gid] = np_sumsq32(a);
}

// ---------------------------------------------------------------------------
// K1c: sampled [B,S,F] -> output sampled_batch [B,F,S] (transpose via LDS)
__global__ __launch_bounds__(256) void transpose_kernel(const float* __restrict__ sampled,
                                                        float* __restrict__ out_samp) {
    __shared__ float tile[32][65];
    int b = blockIdx.x >> 5, sg = blockIdx.x & 31;
    int s0 = sg * 64;
    int tid = threadIdx.x;
    int f = tid & 31, si = tid >> 5;               // si in 0..7
#pragma unroll
    for (int r = 0; r < 8; r++) {
        int s = r * 8 + si;
        tile[f][s] = sampled[((size_t)b * SS + s0 + s) * FF + f];
    }
    __syncthreads();
#pragma unroll
    for (int r = 0; r < 8; r++) {
        int flat = r * 256 + tid;
        int fo = flat >> 6, sw = flat & 63;
        out_samp[((size_t)b * FF + fo) * SS + s0 + sw] = tile[fo][sw];
    }
}

// ---------------------------------------------------------------------------
// K1d v2: x [B,N,F] -> float4-PACKED blocked transpose
// xt[b][t][j][l] (float4), j = f/4, l = lane: point n = t*64+l's features
// 4j..4j+3 sit contiguously at ((t*8+j)*64 + l)*16B. topk lane loads ONE
// global_load_dwordx4 per j: 64 lanes x 16B = 1024B fully coalesced.
__global__ __launch_bounds__(256) void transpose_x_kernel(const float* __restrict__ x,
                                                          float* __restrict__ xt) {
    __shared__ float tile[32][65];
    int b = blockIdx.x >> 8;                // B*256 blocks
    int tg = blockIdx.x & 255;              // tile index t
    int n0 = tg * 64;
    int tid = threadIdx.x;
    int f = tid & 31, si = tid >> 5;        // si in 0..7
#pragma unroll
    for (int r = 0; r < 8; r++) {
        int n = r * 8 + si;
        tile[f][n] = x[((size_t)b * NN + n0 + n) * FF + f];
    }
    __syncthreads();
    float* wo = xt + (((size_t)b * 256 + tg) * 2048);   // 2048 floats/tile
#pragma unroll
    for (int r = 0; r < 8; r++) {
        int flat = r * 256 + tid;           // = j*256 + l*4 + e  (j = r)
        int e = flat & 3, l = (flat >> 2) & 63;
        wo[flat] = tile[4 * r + e][l];
    }
}

// ---------------------------------------------------------------------------
// K2: per-point MLP, h2[b,n,:] = W2 @ relu(W1 @ x + b1) + b2  (fp32, VALU)
__global__ __launch_bounds__(256) void mlp_kernel(const float* __restrict__ x,
                                                  const float* __restrict__ W1,
                                                  const float* __restrict__ b1,
                                                  const float* __restrict__ W2,
                                                  const float* __restrict__ b2,
                                                  float* __restrict__ h2) {
    __shared__ float xs[64][36];          // padded
    __shared__ float hs[8512];            // h1t [128][65] then reused as h2s [64][133]
    int tid = threadIdx.x, lane = tid & 63;
    int wu = __builtin_amdgcn_readfirstlane(tid >> 6);
    size_t p0 = (size_t)blockIdx.x * 64;

    for (int i = tid; i < 64 * 8; i += 256) {
        int row = i >> 3, seg = i & 7;
        *(float4*)&xs[row][seg * 4] = *(const float4*)(x + (p0 + row) * FF + seg * 4);
    }
    __syncthreads();

    float xr[32];
    {
        const float4* r = (const float4*)&xs[lane][0];
#pragma unroll
        for (int j = 0; j < 8; j++) {
            float4 v = r[j];
            xr[4 * j] = v.x; xr[4 * j + 1] = v.y; xr[4 * j + 2] = v.z; xr[4 * j + 3] = v.w;
        }
    }
#pragma unroll 4
    for (int i = 0; i < 32; i++) {
        int o = wu * 32 + i;
        const float4* wr = (const float4*)(W1 + o * FF);
        float a = b1[o];
#pragma unroll
        for (int j = 0; j < 8; j++) {
            float4 v = wr[j];
            a = fmaf(v.x, xr[4 * j], a);     a = fmaf(v.y, xr[4 * j + 1], a);
            a = fmaf(v.z, xr[4 * j + 2], a); a = fmaf(v.w, xr[4 * j + 3], a);
        }
        hs[o * 65 + lane] = fmaxf(a, 0.f);
    }
    __syncthreads();
    float acc[32];
#pragma unroll
    for (int i = 0; i < 32; i++) acc[i] = b2[wu * 32 + i];
    for (int k4 = 0; k4 < 32; k4++) {
        float h0 = hs[(4 * k4 + 0) * 65 + lane];
        float h1v = hs[(4 * k4 + 1) * 65 + lane];
        float h2v = hs[(4 * k4 + 2) * 65 + lane];
        float h3v = hs[(4 * k4 + 3) * 65 + lane];
#pragma unroll
        for (int i = 0; i < 32; i++) {
            const float4 v = *(const float4*)(W2 + (wu * 32 + i) * OUTC + 4 * k4);
            acc[i] = fmaf(v.x, h0, acc[i]);  acc[i] = fmaf(v.y, h1v, acc[i]);
            acc[i] = fmaf(v.z, h2v, acc[i]); acc[i] = fmaf(v.w, h3v, acc[i]);
        }
    }
    __syncthreads();
#pragma unroll 4
    for (int i = 0; i < 32; i++) hs[lane * 133 + wu * 32 + i] = acc[i];
    __syncthreads();
    for (int j = 0; j < 32; j++) {
        int flat = j * 256 + tid;
        int p = flat >> 7, o = flat & 127;
        h2[(p0 + p) * OUTC + o] = hs[p * 133 + o];
    }
}

// ---------------------------------------------------------------------------
// K3 v16: 4 queries/wave with the VGPR CAP REMOVED — 512-thread blocks.
// R9/R11/R13 post-mortem: every 4q attempt spilled, and every one ran at
// the (256,4) cap of 128 VGPRs with ~124 demand -> zero slack -> the
// allocator collapsed to 64 + scratch (VGPR_Count=64 each time). v16 uses
// 8 waves/block at __launch_bounds__(512,2): cap 256, demand ~124, slack
// ~130. Grid = B*S/32 = 512 blocks = exactly 2/CU, no tail. If alloc
// lands <=128 VGPR, HW occupancy = 4 waves/SIMD = 16 waves/CU (same as
// R8) with HALF the L2 bytes (17.2 -> 8.6 GB; R8's wall was 26.6 of
// ~34.5 TB/s). Per-CU VMEM 64 -> 32 MB (~222us at ~60 B/cyc); VALU
// ~100-130us; per-XCD L2 2.4 of 4.3 TB/s -> wall lifted, not shifted.
// Decisive diagnostic: WRITE_SIZE must stay 2048 KB. Any jump -> 4q is
// dead at every cap -> revert to R8 (645us) and declare roofline.
// (R14 was a GPUAcquisitionTimeout — this source is an exact resubmit.)
__device__ __forceinline__ bool lessp(float da, int ia, float db, int ib) {
    return da < db || (da == db && ia < ib);
}
__device__ __forceinline__ void cswap(float& d, int& i, int j, bool dirAsc, int lane) {
    float od = __shfl_xor(d, j);
    int   oi = __shfl_xor(i, j);
    bool lower = (lane & j) == 0;
    bool oLess = lessp(od, oi, d, i);
    if (oLess == (lower == dirAsc)) { d = od; i = oi; }
}
__device__ __forceinline__ void sort64(float& d, int& i, bool asc, int lane) {
#pragma unroll
    for (int k = 2; k <= 64; k <<= 1) {
        bool ba = (((lane & k) == 0) == asc);
#pragma unroll
        for (int j = k >> 1; j > 0; j >>= 1) cswap(d, i, j, ba, lane);
    }
}
// sort m valid slots, keep lowest-64 lex-sorted in [0,64); return 32nd-smallest
__device__ __forceinline__ float wave_compact2(float* bd, int* bi, int m, int lane) {
    float d0 = (lane < m) ? bd[lane] : INFINITY;
    int   i0 = (lane < m) ? bi[lane] : 0x7fffffff;
    float d1 = (lane + 64 < m) ? bd[lane + 64] : INFINITY;
    int   i1 = (lane + 64 < m) ? bi[lane + 64] : 0x7fffffff;
    sort64(d0, i0, true, lane);
    sort64(d1, i1, false, lane);
    bool t = lessp(d1, i1, d0, i0);
    float ld = t ? d1 : d0;
    int   li = t ? i1 : i0;
#pragma unroll
    for (int j = 32; j > 0; j >>= 1) cswap(ld, li, j, true, lane);
    bd[lane] = ld; bi[lane] = li;
    return uni(__shfl(ld, 31));            // uniform across wave
}

__device__ __forceinline__ void insert_cand(float dv, int n, int lane,
                                            float* bd, int* bi, int& cnt, float& tau) {
    unsigned long long m = __ballot(dv < tau);
    if (m) {
        int pos = cnt + mbcnt64(m);
        if (dv < tau) { bd[pos] = dv; bi[pos] = n; }
        cnt += __builtin_popcountll(m);
        if (cnt > 64) { tau = wave_compact2(bd, bi, cnt, lane); cnt = 32; }
    }
}

__global__ __launch_bounds__(512, 2) void topk_kernel(const float* __restrict__ xt,
                                                      const float* __restrict__ x_sq,
                                                      const float* __restrict__ sampled,
                                                      const float* __restrict__ s_sq,
                                                      int* __restrict__ nbr) {
    int b = blockIdx.x & 7;                 // XCD-by-batch swizzle
    int qg = blockIdx.x >> 3;               // 0..63
    int tid = threadIdx.x, lane = tid & 63;
    int w = __builtin_amdgcn_readfirstlane(tid >> 6);   // 0..7
    __shared__ float bufd[32][128];         // 16 KB
    __shared__ int   bufi[32][128];         // 16 KB
    int s0 = qg * 32;                       // 32 queries per block, 4 per wave
    const float* xtb = xt + (size_t)b * (NN * FF);   // packed [256][8][64]f4
    const float* xqb = x_sq + (size_t)b * NN;

    // q0,q1 packed {q0,q1} -> wave-uniform SGPR pairs; q2,q3 -> VGPR-pinned
    v2f qpA[32], qpB[32];
    {
        const float* sp0 = sampled + ((size_t)b * SS + s0 + w * 4 + 0) * FF;
        const float* sp1 = sampled + ((size_t)b * SS + s0 + w * 4 + 1) * FF;
        const float* sp2 = sampled + ((size_t)b * SS + s0 + w * 4 + 2) * FF;
        const float* sp3 = sampled + ((size_t)b * SS + s0 + w * 4 + 3) * FF;
#pragma unroll
        for (int k = 0; k < 32; k++) {
            qpA[k].x = uni(sp0[k]);
            qpA[k].y = uni(sp1[k]);
            qpB[k].x = vpin(sp2[k]);
            qpB[k].y = vpin(sp3[k]);
        }
    }
    v2f ssqA, ssqB;
    ssqA.x = uni(s_sq[b * SS + s0 + w * 4 + 0]);
    ssqA.y = uni(s_sq[b * SS + s0 + w * 4 + 1]);
    ssqB.x = vpin(s_sq[b * SS + s0 + w * 4 + 2]);
    ssqB.y = vpin(s_sq[b * SS + s0 + w * 4 + 3]);

    float* bq0d = &bufd[w * 4 + 0][0];  int* bq0i = &bufi[w * 4 + 0][0];
    float* bq1d = &bufd[w * 4 + 1][0];  int* bq1i = &bufi[w * 4 + 1][0];
    float* bq2d = &bufd[w * 4 + 2][0];  int* bq2i = &bufi[w * 4 + 2][0];
    float* bq3d = &bufd[w * 4 + 3][0];  int* bq3i = &bufi[w * 4 + 3][0];
    int   cnt0 = 0, cnt1 = 0, cnt2 = 0, cnt3 = 0;   // wave-uniform
    float tau0 = INFINITY, tau1 = INFINITY, tau2 = INFINITY, tau3 = INFINITY;

    float xqv = xqb[lane];

    for (int t = 0; t < NN / 64; t++) {
        // lane handles point n = t*64+lane; 8 coalesced dwordx4 loads
        const float4* pn = (const float4*)(xtb + (size_t)t * 2048) + lane;
        float4 vv[8];
#pragma unroll
        for (int j = 0; j < 8; j++) vv[j] = pn[j * 64];
        float xq_c = xqv;
        v2f cA; cA.x = 0.f; cA.y = 0.f;
        v2f cB; cB.x = 0.f; cB.y = 0.f;
#pragma unroll
        for (int j = 0; j < 8; j++) {
            float4 v = vv[j];
            // each half is the ref-exact sequential FMA order f=0..31
            cA = __builtin_elementwise_fma(qpA[4 * j + 0], splat2(v.x), cA);
            cB = __builtin_elementwise_fma(qpB[4 * j + 0], splat2(v.x), cB);
            cA = __builtin_elementwise_fma(qpA[4 * j + 1], splat2(v.y), cA);
            cB = __builtin_elementwise_fma(qpB[4 * j + 1], splat2(v.y), cB);
            cA = __builtin_elementwise_fma(qpA[4 * j + 2], splat2(v.z), cA);
            cB = __builtin_elementwise_fma(qpB[4 * j + 2], splat2(v.z), cB);
            cA = __builtin_elementwise_fma(qpA[4 * j + 3], splat2(v.w), cA);
            cB = __builtin_elementwise_fma(qpB[4 * j + 3], splat2(v.w), cB);
        }
        if (t + 1 < NN / 64) xqv = xqb[(t + 1) * 64 + lane];

        // ref combine order per half: (ssq + xq) - (c + c)
        v2f dA = (ssqA + splat2(xq_c)) - (cA + cA);
        v2f dB = (ssqB + splat2(xq_c)) - (cB + cB);
        int n = t * 64 + lane;
        insert_cand(dA.x, n, lane, bq0d, bq0i, cnt0, tau0);
        insert_cand(dA.y, n, lane, bq1d, bq1i, cnt1, tau1);
        insert_cand(dB.x, n, lane, bq2d, bq2i, cnt2, tau2);
        insert_cand(dB.y, n, lane, bq3d, bq3i, cnt3, tau3);
    }
    // final: compact (lex-sorts survivors) and emit first 32 per query
    wave_compact2(bq0d, bq0i, cnt0, lane);
    wave_compact2(bq1d, bq1i, cnt1, lane);
    wave_compact2(bq2d, bq2i, cnt2, lane);
    wave_compact2(bq3d, bq3i, cnt3, lane);
    int s = s0 + w * 4;
    if (lane < 32) {
        nbr[((size_t)b * SS + s) * KK + lane]     = bq0i[lane];
        nbr[((size_t)b * SS + s + 1) * KK + lane] = bq1i[lane];
        nbr[((size_t)b * SS + s + 2) * KK + lane] = bq2i[lane];
        nbr[((size_t)b * SS + s + 3) * KK + lane] = bq3i[lane];
    }
}

// ---------------------------------------------------------------------------
// K4: features_batch[b,o,s] = max_k h2[b, nbr[b,s,k], o]; block=128, 16 s/block
__global__ __launch_bounds__(128) void maxgather_kernel(const float* __restrict__ h2,
                                                        const int* __restrict__ nbr,
                                                        float* __restrict__ out_feat) {
    __shared__ float fs[128][17];
    int b = blockIdx.x & 7;
    int sg = blockIdx.x >> 3;               // 0..127
    int s0 = sg * 16;
    int tid = threadIdx.x;                  // o = tid (0..127)
    for (int si = 0; si < 16; si++) {
        int s = s0 + si;
        const int* row = nbr + ((size_t)b * SS + s) * KK;
        float m = -INFINITY;
#pragma unroll 4
        for (int k = 0; k < KK; k++) {
            int idx = row[k];
            float v = h2[((size_t)b * NN + idx) * OUTC + tid];
            m = fmaxf(m, v);
        }
        fs[tid][si] = m;
    }
    __syncthreads();
#pragma unroll
    for (int j = 0; j < 16; j++) {
        int flat = j * 128 + tid;
        int fo = flat >> 4, sw = flat & 15;
        out_feat[((size_t)b * OUTC + fo) * SS + s0 + sw] = fs[fo][sw];
    }
}

// ---------------------------------------------------------------------------
extern "C" void kernel_launch(void* const* d_in, const int* in_sizes, int n_in,
                              void* d_out, int out_size, void* d_ws, size_t ws_size,
                              hipStream_t stream) {
    const float* x    = (const float*)d_in[0];
    const int*   sidx = (const int*)d_in[1];
    const float* W1   = (const float*)d_in[2];
    const float* b1   = (const float*)d_in[3];
    const float* W2   = (const float*)d_in[4];
    const float* b2   = (const float*)d_in[5];

    float* out_feat = (float*)d_out;                       // [B,128,S]
    float* out_samp = out_feat + (size_t)BB * OUTC * SS;   // [B,32,S]

    float* h2      = (float*)d_ws;                         // B*N*128 fp32 = 64 MB
    float* sampled = h2 + (size_t)BB * NN * OUTC;          // B*S*F
    float* xsq     = sampled + (size_t)BB * SS * FF;       // B*N
    float* ssq     = xsq + (size_t)BB * NN;                // B*S
    int*   nbr     = (int*)(ssq + (size_t)BB * SS);        // B*S*K
    // xt (16.8 MB) ALIASES the h2 region (64 MB): topk consumes xt strictly
    // before mlp writes h2 (same stream, ordered). No extra workspace.
    float* xt      = h2;

    xsq_kernel<<<dim3(BB * NN / 256), dim3(256), 0, stream>>>(x, xsq);
    gather_kernel<<<dim3(BB * SS / 256), dim3(256), 0, stream>>>(x, sidx, sampled, ssq);
    transpose_kernel<<<dim3(BB * SS / 64), dim3(256), 0, stream>>>(sampled, out_samp);
    transpose_x_kernel<<<dim3(BB * 256), dim3(256), 0, stream>>>(x, xt);
    topk_kernel<<<dim3(BB * SS / 32), dim3(512), 0, stream>>>(xt, xsq, sampled, ssq, nbr);
    mlp_kernel<<<dim3(BB * NN / 64), dim3(256), 0, stream>>>(x, W1, b1, W2, b2, h2);
    maxgather_kernel<<<dim3(BB * SS / 16), dim3(128), 0, stream>>>(h2, nbr, out_feat);
}

// Round 16
// 968.554 us; speedup vs baseline: 2.2025x; 1.0311x over previous
//
#include <hip/hip_runtime.h>
#include <math.h>

#pragma clang fp contract(off)   // no implicit fusion; FMA only where ref has it

// Problem constants (fixed by the reference)
#define BB   8
#define NN   16384
#define FF   32
#define SS   2048
#define KK   32
#define OUTC 128

typedef float v2f __attribute__((ext_vector_type(2)));

// force a value into uniform (SGPR) representation
__device__ __forceinline__ float uni(float v) {
    return __uint_as_float(__builtin_amdgcn_readfirstlane(__float_as_uint(v)));
}

// pin a value into a VGPR (blocks scalarization/remat of the producing load)
__device__ __forceinline__ float vpin(float v) {
    float r;
    asm volatile("v_mov_b32 %0, %1" : "=v"(r) : "v"(v));
    return r;
}

__device__ __forceinline__ v2f splat2(float s) { v2f r; r.x = s; r.y = s; return r; }

// prefix popcount of 64-bit ballot below this lane (2 VALU ops)
__device__ __forceinline__ int mbcnt64(unsigned long long m) {
    return __builtin_amdgcn_mbcnt_hi((unsigned)(m >> 32),
           __builtin_amdgcn_mbcnt_lo((unsigned)m, 0));
}

// ---------------------------------------------------------------------------
// Reference-bit-exact fp32 helpers (validated R0-R7):
// x_sq / s_sq: numpy pairwise_sum scalar 8-accumulator block (n=32, no FMA)
__device__ __forceinline__ float np_sumsq32(const float* a) {
    float r[8];
#pragma unroll
    for (int j = 0; j < 8; j++) r[j] = a[j] * a[j];
#pragma unroll
    for (int t = 1; t < 4; t++) {
#pragma unroll
        for (int j = 0; j < 8; j++) {
            float e = a[8 * t + j] * a[8 * t + j];
            r[j] = r[j] + e;
        }
    }
    return ((r[0] + r[1]) + (r[2] + r[3])) + ((r[4] + r[5]) + (r[6] + r[7]));
}

// ---------------------------------------------------------------------------
// K1a: x_sq[b,n] = ref-order sum_f x^2
__global__ __launch_bounds__(256) void xsq_kernel(const float* __restrict__ x,
                                                  float* __restrict__ xsq) {
    int gid = blockIdx.x * 256 + threadIdx.x;      // < B*N
    const float4* r = (const float4*)(x + (size_t)gid * FF);
    float a[32];
#pragma unroll
    for (int j = 0; j < 8; j++) {
        float4 v = r[j];
        a[4 * j] = v.x; a[4 * j + 1] = v.y; a[4 * j + 2] = v.z; a[4 * j + 3] = v.w;
    }
    xsq[gid] = np_sumsq32(a);
}

// ---------------------------------------------------------------------------
// K1b: gather sampled features (row-major [B,S,F]) + ref-order s_sq
__global__ __launch_bounds__(256) void gather_kernel(const float* __restrict__ x,
                                                     const int* __restrict__ sidx,
                                                     float* __restrict__ sampled,
                                                     float* __restrict__ ssq) {
    int gid = blockIdx.x * 256 + threadIdx.x;      // < B*S
    int b = gid >> 11;
    int idx = sidx[gid];
    const float4* r = (const float4*)(x + ((size_t)b * NN + idx) * FF);
    float4* wo = (float4*)(sampled + (size_t)gid * FF);
    float a[32];
#pragma unroll
    for (int j = 0; j < 8; j++) {
        float4 v = r[j];
        a[4 * j] = v.x; a[4 * j + 1] = v.y; a[4 * j + 2] = v.z; a[4 * j + 3] = v.w;
        wo[j] = v;
    }
    ssq[gid] = np_sumsq32(a);
}

// ---------------------------------------------------------------------------
// K1c: sampled [B,S,F] -> output sampled_batch [B,F,S] (transpose via LDS)
__global__ __launch_bounds__(256) void transpose_kernel(const float* __restrict__ sampled,
                                                        float* __restrict__ out_samp) {
    __shared__ float tile[32][65];
    int b = blockIdx.x >> 5, sg = blockIdx.x & 31;
    int s0 = sg * 64;
    int tid = threadIdx.x;
    int f = tid & 31, si = tid >> 5;               // si in 0..7
#pragma unroll
    for (int r = 0; r < 8; r++) {
        int s = r * 8 + si;
        tile[f][s] = sampled[((size_t)b * SS + s0 + s) * FF + f];
    }
    __syncthreads();
#pragma unroll
    for (int r = 0; r < 8; r++) {
        int flat = r * 256 + tid;
        int fo = flat >> 6, sw = flat & 63;
        out_samp[((size_t)b * FF + fo) * SS + s0 + sw] = tile[fo][sw];
    }
}

// ---------------------------------------------------------------------------
// K1d v2: x [B,N,F] -> float4-PACKED blocked transpose
// xt[b][t][j][l] (float4), j = f/4, l = lane: point n = t*64+l's features
// 4j..4j+3 sit contiguously at ((t*8+j)*64 + l)*16B. topk lane loads ONE
// global_load_dwordx4 per j: 64 lanes x 16B = 1024B fully coalesced.
__global__ __launch_bounds__(256) void transpose_x_kernel(const float* __restrict__ x,
                                                          float* __restrict__ xt) {
    __shared__ float tile[32][65];
    int b = blockIdx.x >> 8;                // B*256 blocks
    int tg = blockIdx.x & 255;              // tile index t
    int n0 = tg * 64;
    int tid = threadIdx.x;
    int f = tid & 31, si = tid >> 5;        // si in 0..7
#pragma unroll
    for (int r = 0; r < 8; r++) {
        int n = r * 8 + si;
        tile[f][n] = x[((size_t)b * NN + n0 + n) * FF + f];
    }
    __syncthreads();
    float* wo = xt + (((size_t)b * 256 + tg) * 2048);   // 2048 floats/tile
#pragma unroll
    for (int r = 0; r < 8; r++) {
        int flat = r * 256 + tid;           // = j*256 + l*4 + e  (j = r)
        int e = flat & 3, l = (flat >> 2) & 63;
        wo[flat] = tile[4 * r + e][l];
    }
}

// ---------------------------------------------------------------------------
// K2: per-point MLP, h2[b,n,:] = W2 @ relu(W1 @ x + b1) + b2  (fp32, VALU)
__global__ __launch_bounds__(256) void mlp_kernel(const float* __restrict__ x,
                                                  const float* __restrict__ W1,
                                                  const float* __restrict__ b1,
                                                  const float* __restrict__ W2,
                                                  const float* __restrict__ b2,
                                                  float* __restrict__ h2) {
    __shared__ float xs[64][36];          // padded
    __shared__ float hs[8512];            // h1t [128][65] then reused as h2s [64][133]
    int tid = threadIdx.x, lane = tid & 63;
    int wu = __builtin_amdgcn_readfirstlane(tid >> 6);
    size_t p0 = (size_t)blockIdx.x * 64;

    for (int i = tid; i < 64 * 8; i += 256) {
        int row = i >> 3, seg = i & 7;
        *(float4*)&xs[row][seg * 4] = *(const float4*)(x + (p0 + row) * FF + seg * 4);
    }
    __syncthreads();

    float xr[32];
    {
        const float4* r = (const float4*)&xs[lane][0];
#pragma unroll
        for (int j = 0; j < 8; j++) {
            float4 v = r[j];
            xr[4 * j] = v.x; xr[4 * j + 1] = v.y; xr[4 * j + 2] = v.z; xr[4 * j + 3] = v.w;
        }
    }
#pragma unroll 4
    for (int i = 0; i < 32; i++) {
        int o = wu * 32 + i;
        const float4* wr = (const float4*)(W1 + o * FF);
        float a = b1[o];
#pragma unroll
        for (int j = 0; j < 8; j++) {
            float4 v = wr[j];
            a = fmaf(v.x, xr[4 * j], a);     a = fmaf(v.y, xr[4 * j + 1], a);
            a = fmaf(v.z, xr[4 * j + 2], a); a = fmaf(v.w, xr[4 * j + 3], a);
        }
        hs[o * 65 + lane] = fmaxf(a, 0.f);
    }
    __syncthreads();
    float acc[32];
#pragma unroll
    for (int i = 0; i < 32; i++) acc[i] = b2[wu * 32 + i];
    for (int k4 = 0; k4 < 32; k4++) {
        float h0 = hs[(4 * k4 + 0) * 65 + lane];
        float h1v = hs[(4 * k4 + 1) * 65 + lane];
        float h2v = hs[(4 * k4 + 2) * 65 + lane];
        float h3v = hs[(4 * k4 + 3) * 65 + lane];
#pragma unroll
        for (int i = 0; i < 32; i++) {
            const float4 v = *(const float4*)(W2 + (wu * 32 + i) * OUTC + 4 * k4);
            acc[i] = fmaf(v.x, h0, acc[i]);  acc[i] = fmaf(v.y, h1v, acc[i]);
            acc[i] = fmaf(v.z, h2v, acc[i]); acc[i] = fmaf(v.w, h3v, acc[i]);
        }
    }
    __syncthreads();
#pragma unroll 4
    for (int i = 0; i < 32; i++) hs[lane * 133 + wu * 32 + i] = acc[i];
    __syncthreads();
    for (int j = 0; j < 32; j++) {
        int flat = j * 256 + tid;
        int p = flat >> 7, o = flat & 127;
        h2[(p0 + p) * OUTC + o] = hs[p * 133 + o];
    }
}

// ---------------------------------------------------------------------------
// K3 v17: 4 queries/wave, 256-THREAD blocks, __launch_bounds__(256, 2).
// R15 post-mortem: (512,2) finally killed the spill (VGPR=84 allocated,
// WRITE=2048KB clean) but 512-thread blocks need 2 waves on EVERY SIMD
// simultaneously -> residency collapsed to ~8 waves/CU (occ 23%) -> 723us,
// WORSE than R8's 645. Lesson: the R9/R11/R13 spills were purely the
// (256,4) 128-VGPR cap; (256,2) gives cap 256 with 256-thread blocks.
// True 4q demand is 84 VGPR (R15 measured), so (256,2) has ~170 slack.
// Grid = B*S/16 = 1024 = exactly 4 blocks/CU = 16 waves/CU — SAME TLP as
// R8 with HALF the L2 bytes (8.6 GB). This isolates byte-halving from the
// wave-count change R15 conflated.
// Decision rule: dur >= 645 with clean counters -> bytes/query lever is
// exhausted -> revert to R8, declare structure roofline.
__device__ __forceinline__ bool lessp(float da, int ia, float db, int ib) {
    return da < db || (da == db && ia < ib);
}
__device__ __forceinline__ void cswap(float& d, int& i, int j, bool dirAsc, int lane) {
    float od = __shfl_xor(d, j);
    int   oi = __shfl_xor(i, j);
    bool lower = (lane & j) == 0;
    bool oLess = lessp(od, oi, d, i);
    if (oLess == (lower == dirAsc)) { d = od; i = oi; }
}
__device__ __forceinline__ void sort64(float& d, int& i, bool asc, int lane) {
#pragma unroll
    for (int k = 2; k <= 64; k <<= 1) {
        bool ba = (((lane & k) == 0) == asc);
#pragma unroll
        for (int j = k >> 1; j > 0; j >>= 1) cswap(d, i, j, ba, lane);
    }
}
// sort m valid slots, keep lowest-64 lex-sorted in [0,64); return 32nd-smallest
__device__ __forceinline__ float wave_compact2(float* bd, int* bi, int m, int lane) {
    float d0 = (lane < m) ? bd[lane] : INFINITY;
    int   i0 = (lane < m) ? bi[lane] : 0x7fffffff;
    float d1 = (lane + 64 < m) ? bd[lane + 64] : INFINITY;
    int   i1 = (lane + 64 < m) ? bi[lane + 64] : 0x7fffffff;
    sort64(d0, i0, true, lane);
    sort64(d1, i1, false, lane);
    bool t = lessp(d1, i1, d0, i0);
    float ld = t ? d1 : d0;
    int   li = t ? i1 : i0;
#pragma unroll
    for (int j = 32; j > 0; j >>= 1) cswap(ld, li, j, true, lane);
    bd[lane] = ld; bi[lane] = li;
    return uni(__shfl(ld, 31));            // uniform across wave
}

__device__ __forceinline__ void insert_cand(float dv, int n, int lane,
                                            float* bd, int* bi, int& cnt, float& tau) {
    unsigned long long m = __ballot(dv < tau);
    if (m) {
        int pos = cnt + mbcnt64(m);
        if (dv < tau) { bd[pos] = dv; bi[pos] = n; }
        cnt += __builtin_popcountll(m);
        if (cnt > 64) { tau = wave_compact2(bd, bi, cnt, lane); cnt = 32; }
    }
}

__global__ __launch_bounds__(256, 2) void topk_kernel(const float* __restrict__ xt,
                                                      const float* __restrict__ x_sq,
                                                      const float* __restrict__ sampled,
                                                      const float* __restrict__ s_sq,
                                                      int* __restrict__ nbr) {
    int b = blockIdx.x & 7;                 // XCD-by-batch swizzle
    int qg = blockIdx.x >> 3;               // 0..127
    int tid = threadIdx.x, lane = tid & 63;
    int w = __builtin_amdgcn_readfirstlane(tid >> 6);   // 0..3
    __shared__ float bufd[16][128];         // 8 KB
    __shared__ int   bufi[16][128];         // 8 KB
    int s0 = qg * 16;                       // 16 queries per block, 4 per wave
    const float* xtb = xt + (size_t)b * (NN * FF);   // packed [256][8][64]f4
    const float* xqb = x_sq + (size_t)b * NN;

    // q0,q1 packed {q0,q1} -> wave-uniform SGPR pairs; q2,q3 -> VGPR-pinned
    v2f qpA[32], qpB[32];
    {
        const float* sp0 = sampled + ((size_t)b * SS + s0 + w * 4 + 0) * FF;
        const float* sp1 = sampled + ((size_t)b * SS + s0 + w * 4 + 1) * FF;
        const float* sp2 = sampled + ((size_t)b * SS + s0 + w * 4 + 2) * FF;
        const float* sp3 = sampled + ((size_t)b * SS + s0 + w * 4 + 3) * FF;
#pragma unroll
        for (int k = 0; k < 32; k++) {
            qpA[k].x = uni(sp0[k]);
            qpA[k].y = uni(sp1[k]);
            qpB[k].x = vpin(sp2[k]);
            qpB[k].y = vpin(sp3[k]);
        }
    }
    v2f ssqA, ssqB;
    ssqA.x = uni(s_sq[b * SS + s0 + w * 4 + 0]);
    ssqA.y = uni(s_sq[b * SS + s0 + w * 4 + 1]);
    ssqB.x = vpin(s_sq[b * SS + s0 + w * 4 + 2]);
    ssqB.y = vpin(s_sq[b * SS + s0 + w * 4 + 3]);

    float* bq0d = &bufd[w * 4 + 0][0];  int* bq0i = &bufi[w * 4 + 0][0];
    float* bq1d = &bufd[w * 4 + 1][0];  int* bq1i = &bufi[w * 4 + 1][0];
    float* bq2d = &bufd[w * 4 + 2][0];  int* bq2i = &bufi[w * 4 + 2][0];
    float* bq3d = &bufd[w * 4 + 3][0];  int* bq3i = &bufi[w * 4 + 3][0];
    int   cnt0 = 0, cnt1 = 0, cnt2 = 0, cnt3 = 0;   // wave-uniform
    float tau0 = INFINITY, tau1 = INFINITY, tau2 = INFINITY, tau3 = INFINITY;

    float xqv = xqb[lane];

    for (int t = 0; t < NN / 64; t++) {
        // lane handles point n = t*64+lane; 8 coalesced dwordx4 loads
        const float4* pn = (const float4*)(xtb + (size_t)t * 2048) + lane;
        float4 vv[8];
#pragma unroll
        for (int j = 0; j < 8; j++) vv[j] = pn[j * 64];
        float xq_c = xqv;
        v2f cA; cA.x = 0.f; cA.y = 0.f;
        v2f cB; cB.x = 0.f; cB.y = 0.f;
#pragma unroll
        for (int j = 0; j < 8; j++) {
            float4 v = vv[j];
            // each half is the ref-exact sequential FMA order f=0..31
            cA = __builtin_elementwise_fma(qpA[4 * j + 0], splat2(v.x), cA);
            cB = __builtin_elementwise_fma(qpB[4 * j + 0], splat2(v.x), cB);
            cA = __builtin_elementwise_fma(qpA[4 * j + 1], splat2(v.y), cA);
            cB = __builtin_elementwise_fma(qpB[4 * j + 1], splat2(v.y), cB);
            cA = __builtin_elementwise_fma(qpA[4 * j + 2], splat2(v.z), cA);
            cB = __builtin_elementwise_fma(qpB[4 * j + 2], splat2(v.z), cB);
            cA = __builtin_elementwise_fma(qpA[4 * j + 3], splat2(v.w), cA);
            cB = __builtin_elementwise_fma(qpB[4 * j + 3], splat2(v.w), cB);
        }
        if (t + 1 < NN / 64) xqv = xqb[(t + 1) * 64 + lane];

        // ref combine order per half: (ssq + xq) - (c + c)
        v2f dA = (ssqA + splat2(xq_c)) - (cA + cA);
        v2f dB = (ssqB + splat2(xq_c)) - (cB + cB);
        int n = t * 64 + lane;
        insert_cand(dA.x, n, lane, bq0d, bq0i, cnt0, tau0);
        insert_cand(dA.y, n, lane, bq1d, bq1i, cnt1, tau1);
        insert_cand(dB.x, n, lane, bq2d, bq2i, cnt2, tau2);
        insert_cand(dB.y, n, lane, bq3d, bq3i, cnt3, tau3);
    }
    // final: compact (lex-sorts survivors) and emit first 32 per query
    wave_compact2(bq0d, bq0i, cnt0, lane);
    wave_compact2(bq1d, bq1i, cnt1, lane);
    wave_compact2(bq2d, bq2i, cnt2, lane);
    wave_compact2(bq3d, bq3i, cnt3, lane);
    int s = s0 + w * 4;
    if (lane < 32) {
        nbr[((size_t)b * SS + s) * KK + lane]     = bq0i[lane];
        nbr[((size_t)b * SS + s + 1) * KK + lane] = bq1i[lane];
        nbr[((size_t)b * SS + s + 2) * KK + lane] = bq2i[lane];
        nbr[((size_t)b * SS + s + 3) * KK + lane] = bq3i[lane];
    }
}

// ---------------------------------------------------------------------------
// K4: features_batch[b,o,s] = max_k h2[b, nbr[b,s,k], o]; block=128, 16 s/block
__global__ __launch_bounds__(128) void maxgather_kernel(const float* __restrict__ h2,
                                                        const int* __restrict__ nbr,
                                                        float* __restrict__ out_feat) {
    __shared__ float fs[128][17];
    int b = blockIdx.x & 7;
    int sg = blockIdx.x >> 3;               // 0..127
    int s0 = sg * 16;
    int tid = threadIdx.x;                  // o = tid (0..127)
    for (int si = 0; si < 16; si++) {
        int s = s0 + si;
        const int* row = nbr + ((size_t)b * SS + s) * KK;
        float m = -INFINITY;
#pragma unroll 4
        for (int k = 0; k < KK; k++) {
            int idx = row[k];
            float v = h2[((size_t)b * NN + idx) * OUTC + tid];
            m = fmaxf(m, v);
        }
        fs[tid][si] = m;
    }
    __syncthreads();
#pragma unroll
    for (int j = 0; j < 16; j++) {
        int flat = j * 128 + tid;
        int fo = flat >> 4, sw = flat & 15;
        out_feat[((size_t)b * OUTC + fo) * SS + s0 + sw] = fs[fo][sw];
    }
}

// ---------------------------------------------------------------------------
extern "C" void kernel_launch(void* const* d_in, const int* in_sizes, int n_in,
                              void* d_out, int out_size, void* d_ws, size_t ws_size,
                              hipStream_t stream) {
    const float* x    = (const float*)d_in[0];
    const int*   sidx = (const int*)d_in[1];
    const float* W1   = (const float*)d_in[2];
    const float* b1   = (const float*)d_in[3];
    const float* W2   = (const float*)d_in[4];
    const float* b2   = (const float*)d_in[5];

    float* out_feat = (float*)d_out;                       // [B,128,S]
    float* out_samp = out_feat + (size_t)BB * OUTC * SS;   // [B,32,S]

    float* h2      = (float*)d_ws;                         // B*N*128 fp32 = 64 MB
    float* sampled = h2 + (size_t)BB * NN * OUTC;          // B*S*F
    float* xsq     = sampled + (size_t)BB * SS * FF;       // B*N
    float* ssq     = xsq + (size_t)BB * NN;                // B*S
    int*   nbr     = (int*)(ssq + (size_t)BB * SS);        // B*S*K
    // xt (16.8 MB) ALIASES the h2 region (64 MB): topk consumes xt strictly
    // before mlp writes h2 (same stream, ordered). No extra workspace.
    float* xt      = h2;

    xsq_kernel<<<dim3(BB * NN / 256), dim3(256), 0, stream>>>(x, xsq);
    gather_kernel<<<dim3(BB * SS / 256), dim3(256), 0, stream>>>(x, sidx, sampled, ssq);
    transpose_kernel<<<dim3(BB * SS / 64), dim3(256), 0, stream>>>(sampled, out_samp);
    transpose_x_kernel<<<dim3(BB * 256), dim3(256), 0, stream>>>(x, xt);
    topk_kernel<<<dim3(BB * SS / 16), dim3(256), 0, stream>>>(xt, xsq, sampled, ssq, nbr);
    mlp_kernel<<<dim3(BB * NN / 64), dim3(256), 0, stream>>>(x, W1, b1, W2, b2, h2);
    maxgather_kernel<<<dim3(BB * SS / 16), dim3(128), 0, stream>>>(h2, nbr, out_feat);
}

// Round 17
// 901.256 us; speedup vs baseline: 2.3670x; 1.0747x over previous
//
#include <hip/hip_runtime.h>
#include <math.h>

#pragma clang fp contract(off)   // no implicit fusion; FMA only where ref has it

// Problem constants (fixed by the reference)
#define BB   8
#define NN   16384
#define FF   32
#define SS   2048
#define KK   32
#define OUTC 128

typedef float v2f __attribute__((ext_vector_type(2)));

// force a value into uniform (SGPR) representation
__device__ __forceinline__ float uni(float v) {
    return __uint_as_float(__builtin_amdgcn_readfirstlane(__float_as_uint(v)));
}

__device__ __forceinline__ v2f splat2(float s) { v2f r; r.x = s; r.y = s; return r; }

// prefix popcount of 64-bit ballot below this lane (2 VALU ops)
__device__ __forceinline__ int mbcnt64(unsigned long long m) {
    return __builtin_amdgcn_mbcnt_hi((unsigned)(m >> 32),
           __builtin_amdgcn_mbcnt_lo((unsigned)m, 0));
}

// ---------------------------------------------------------------------------
// Reference-bit-exact fp32 helpers (validated R0-R7):
// x_sq / s_sq: numpy pairwise_sum scalar 8-accumulator block (n=32, no FMA)
__device__ __forceinline__ float np_sumsq32(const float* a) {
    float r[8];
#pragma unroll
    for (int j = 0; j < 8; j++) r[j] = a[j] * a[j];
#pragma unroll
    for (int t = 1; t < 4; t++) {
#pragma unroll
        for (int j = 0; j < 8; j++) {
            float e = a[8 * t + j] * a[8 * t + j];
            r[j] = r[j] + e;
        }
    }
    return ((r[0] + r[1]) + (r[2] + r[3])) + ((r[4] + r[5]) + (r[6] + r[7]));
}

// ---------------------------------------------------------------------------
// K1a: x_sq[b,n] = ref-order sum_f x^2
__global__ __launch_bounds__(256) void xsq_kernel(const float* __restrict__ x,
                                                  float* __restrict__ xsq) {
    int gid = blockIdx.x * 256 + threadIdx.x;      // < B*N
    const float4* r = (const float4*)(x + (size_t)gid * FF);
    float a[32];
#pragma unroll
    for (int j = 0; j < 8; j++) {
        float4 v = r[j];
        a[4 * j] = v.x; a[4 * j + 1] = v.y; a[4 * j + 2] = v.z; a[4 * j + 3] = v.w;
    }
    xsq[gid] = np_sumsq32(a);
}

// ---------------------------------------------------------------------------
// K1b: gather sampled features (row-major [B,S,F]) + ref-order s_sq
__global__ __launch_bounds__(256) void gather_kernel(const float* __restrict__ x,
                                                     const int* __restrict__ sidx,
                                                     float* __restrict__ sampled,
                                                     float* __restrict__ ssq) {
    int gid = blockIdx.x * 256 + threadIdx.x;      // < B*S
    int b = gid >> 11;
    int idx = sidx[gid];
    const float4* r = (const float4*)(x + ((size_t)b * NN + idx) * FF);
    float4* wo = (float4*)(sampled + (size_t)gid * FF);
    float a[32];
#pragma unroll
    for (int j = 0; j < 8; j++) {
        float4 v = r[j];
        a[4 * j] = v.x; a[4 * j + 1] = v.y; a[4 * j + 2] = v.z; a[4 * j + 3] = v.w;
        wo[j] = v;
    }
    ssq[gid] = np_sumsq32(a);
}

// ---------------------------------------------------------------------------
// K1c: sampled [B,S,F] -> output sampled_batch [B,F,S] (transpose via LDS)
__global__ __launch_bounds__(256) void transpose_kernel(const float* __restrict__ sampled,
                                                        float* __restrict__ out_samp) {
    __shared__ float tile[32][65];
    int b = blockIdx.x >> 5, sg = blockIdx.x & 31;
    int s0 = sg * 64;
    int tid = threadIdx.x;
    int f = tid & 31, si = tid >> 5;               // si in 0..7
#pragma unroll
    for (int r = 0; r < 8; r++) {
        int s = r * 8 + si;
        tile[f][s] = sampled[((size_t)b * SS + s0 + s) * FF + f];
    }
    __syncthreads();
#pragma unroll
    for (int r = 0; r < 8; r++) {
        int flat = r * 256 + tid;
        int fo = flat >> 6, sw = flat & 63;
        out_samp[((size_t)b * FF + fo) * SS + s0 + sw] = tile[fo][sw];
    }
}

// ---------------------------------------------------------------------------
// K1d v2: x [B,N,F] -> float4-PACKED blocked transpose
// xt[b][t][j][l] (float4), j = f/4, l = lane: point n = t*64+l's features
// 4j..4j+3 sit contiguously at ((t*8+j)*64 + l)*16B. topk lane loads ONE
// global_load_dwordx4 per j: 64 lanes x 16B = 1024B fully coalesced.
__global__ __launch_bounds__(256) void transpose_x_kernel(const float* __restrict__ x,
                                                          float* __restrict__ xt) {
    __shared__ float tile[32][65];
    int b = blockIdx.x >> 8;                // B*256 blocks
    int tg = blockIdx.x & 255;              // tile index t
    int n0 = tg * 64;
    int tid = threadIdx.x;
    int f = tid & 31, si = tid >> 5;        // si in 0..7
#pragma unroll
    for (int r = 0; r < 8; r++) {
        int n = r * 8 + si;
        tile[f][n] = x[((size_t)b * NN + n0 + n) * FF + f];
    }
    __syncthreads();
    float* wo = xt + (((size_t)b * 256 + tg) * 2048);   // 2048 floats/tile
#pragma unroll
    for (int r = 0; r < 8; r++) {
        int flat = r * 256 + tid;           // = j*256 + l*4 + e  (j = r)
        int e = flat & 3, l = (flat >> 2) & 63;
        wo[flat] = tile[4 * r + e][l];
    }
}

// ---------------------------------------------------------------------------
// K2: per-point MLP, h2[b,n,:] = W2 @ relu(W1 @ x + b1) + b2  (fp32, VALU)
__global__ __launch_bounds__(256) void mlp_kernel(const float* __restrict__ x,
                                                  const float* __restrict__ W1,
                                                  const float* __restrict__ b1,
                                                  const float* __restrict__ W2,
                                                  const float* __restrict__ b2,
                                                  float* __restrict__ h2) {
    __shared__ float xs[64][36];          // padded
    __shared__ float hs[8512];            // h1t [128][65] then reused as h2s [64][133]
    int tid = threadIdx.x, lane = tid & 63;
    int wu = __builtin_amdgcn_readfirstlane(tid >> 6);
    size_t p0 = (size_t)blockIdx.x * 64;

    for (int i = tid; i < 64 * 8; i += 256) {
        int row = i >> 3, seg = i & 7;
        *(float4*)&xs[row][seg * 4] = *(const float4*)(x + (p0 + row) * FF + seg * 4);
    }
    __syncthreads();

    float xr[32];
    {
        const float4* r = (const float4*)&xs[lane][0];
#pragma unroll
        for (int j = 0; j < 8; j++) {
            float4 v = r[j];
            xr[4 * j] = v.x; xr[4 * j + 1] = v.y; xr[4 * j + 2] = v.z; xr[4 * j + 3] = v.w;
        }
    }
#pragma unroll 4
    for (int i = 0; i < 32; i++) {
        int o = wu * 32 + i;
        const float4* wr = (const float4*)(W1 + o * FF);
        float a = b1[o];
#pragma unroll
        for (int j = 0; j < 8; j++) {
            float4 v = wr[j];
            a = fmaf(v.x, xr[4 * j], a);     a = fmaf(v.y, xr[4 * j + 1], a);
            a = fmaf(v.z, xr[4 * j + 2], a); a = fmaf(v.w, xr[4 * j + 3], a);
        }
        hs[o * 65 + lane] = fmaxf(a, 0.f);
    }
    __syncthreads();
    float acc[32];
#pragma unroll
    for (int i = 0; i < 32; i++) acc[i] = b2[wu * 32 + i];
    for (int k4 = 0; k4 < 32; k4++) {
        float h0 = hs[(4 * k4 + 0) * 65 + lane];
        float h1v = hs[(4 * k4 + 1) * 65 + lane];
        float h2v = hs[(4 * k4 + 2) * 65 + lane];
        float h3v = hs[(4 * k4 + 3) * 65 + lane];
#pragma unroll
        for (int i = 0; i < 32; i++) {
            const float4 v = *(const float4*)(W2 + (wu * 32 + i) * OUTC + 4 * k4);
            acc[i] = fmaf(v.x, h0, acc[i]);  acc[i] = fmaf(v.y, h1v, acc[i]);
            acc[i] = fmaf(v.z, h2v, acc[i]); acc[i] = fmaf(v.w, h3v, acc[i]);
        }
    }
    __syncthreads();
#pragma unroll 4
    for (int i = 0; i < 32; i++) hs[lane * 133 + wu * 32 + i] = acc[i];
    __syncthreads();
    for (int j = 0; j < 32; j++) {
        int flat = j * 256 + tid;
        int p = flat >> 7, o = flat & 127;
        h2[(p0 + p) * OUTC + o] = hs[p * 133 + o];
    }
}

// ---------------------------------------------------------------------------
// K3 v11 (FINAL, reverted from R16): 2 queries/wave register-direct loop
// over float4-packed transposed x. Best verified: topk 645us, total 903us.
// Session findings baked into this choice:
// - LDS-staged broadcast (R0-R6): capped ~780us by LDS-pipe + barrier cost.
// - v11 (R8): no LDS, no barriers, 8 coalesced dwordx4/tile, 2q in SGPRs.
//   645us @ VALUBusy 61%, occ 54%, 17.2 GB L2 read (26.6 TB/s achieved).
// - Bytes/query reduction (4q/wave) tested 4 ways: VGPR (R9/R11: spilled at
//   the (256,4)=128 cap), LDS-broadcast (R13: spilled), (512,2) clean but
//   occ-collapsed (R15: 723us), (256,2) clean 84 VGPR (R16: 695us, occ 25%).
//   Clean tests PROVE the kernel is latency/TLP-bound, not L2-BW-bound:
//   halving bytes while halving waves loses. 2q/28-VGPR maximizes TLP.
// - Lockstep barrier for L1 reuse (R12): regressed (+130us coupling).
// Remaining stall (39% at occ 54%) = dependent L2-load->FMA chains + serial
// shuffle-based compact chains; structural to this algorithm.
__device__ __forceinline__ bool lessp(float da, int ia, float db, int ib) {
    return da < db || (da == db && ia < ib);
}
__device__ __forceinline__ void cswap(float& d, int& i, int j, bool dirAsc, int lane) {
    float od = __shfl_xor(d, j);
    int   oi = __shfl_xor(i, j);
    bool lower = (lane & j) == 0;
    bool oLess = lessp(od, oi, d, i);
    if (oLess == (lower == dirAsc)) { d = od; i = oi; }
}
__device__ __forceinline__ void sort64(float& d, int& i, bool asc, int lane) {
#pragma unroll
    for (int k = 2; k <= 64; k <<= 1) {
        bool ba = (((lane & k) == 0) == asc);
#pragma unroll
        for (int j = k >> 1; j > 0; j >>= 1) cswap(d, i, j, ba, lane);
    }
}
// sort m valid slots, keep lowest-64 lex-sorted in [0,64); return 32nd-smallest
__device__ __forceinline__ float wave_compact2(float* bd, int* bi, int m, int lane) {
    float d0 = (lane < m) ? bd[lane] : INFINITY;
    int   i0 = (lane < m) ? bi[lane] : 0x7fffffff;
    float d1 = (lane + 64 < m) ? bd[lane + 64] : INFINITY;
    int   i1 = (lane + 64 < m) ? bi[lane + 64] : 0x7fffffff;
    sort64(d0, i0, true, lane);
    sort64(d1, i1, false, lane);
    bool t = lessp(d1, i1, d0, i0);
    float ld = t ? d1 : d0;
    int   li = t ? i1 : i0;
#pragma unroll
    for (int j = 32; j > 0; j >>= 1) cswap(ld, li, j, true, lane);
    bd[lane] = ld; bi[lane] = li;
    return uni(__shfl(ld, 31));            // uniform across wave
}

__device__ __forceinline__ void insert_cand(float dv, int n, int lane,
                                            float* bd, int* bi, int& cnt, float& tau) {
    unsigned long long m = __ballot(dv < tau);
    if (m) {
        int pos = cnt + mbcnt64(m);
        if (dv < tau) { bd[pos] = dv; bi[pos] = n; }
        cnt += __builtin_popcountll(m);
        if (cnt > 64) { tau = wave_compact2(bd, bi, cnt, lane); cnt = 32; }
    }
}

__global__ __launch_bounds__(256, 6) void topk_kernel(const float* __restrict__ xt,
                                                      const float* __restrict__ x_sq,
                                                      const float* __restrict__ sampled,
                                                      const float* __restrict__ s_sq,
                                                      int* __restrict__ nbr) {
    int b = blockIdx.x & 7;                 // XCD-by-batch swizzle
    int qg = blockIdx.x >> 3;               // 0..255
    int tid = threadIdx.x, lane = tid & 63;
    int w = __builtin_amdgcn_readfirstlane(tid >> 6);
    __shared__ float bufd[8][128];
    __shared__ int   bufi[8][128];
    int s0 = qg * 8;                        // 8 queries per block, 2 per wave
    const float* xtb = xt + (size_t)b * (NN * FF);   // packed [256][8][64]f4
    const float* xqb = x_sq + (size_t)b * NN;

    // 2 query feature vectors, packed {q0,q1} pairs -> wave-uniform (SGPR pairs)
    v2f qp[32];
    {
        const float* sp0 = sampled + ((size_t)b * SS + s0 + w * 2 + 0) * FF;
        const float* sp1 = sampled + ((size_t)b * SS + s0 + w * 2 + 1) * FF;
#pragma unroll
        for (int k = 0; k < 32; k++) {
            qp[k].x = uni(sp0[k]);
            qp[k].y = uni(sp1[k]);
        }
    }
    v2f ssq01;
    ssq01.x = uni(s_sq[b * SS + s0 + w * 2 + 0]);
    ssq01.y = uni(s_sq[b * SS + s0 + w * 2 + 1]);

    float* bq0d = &bufd[w * 2 + 0][0];  int* bq0i = &bufi[w * 2 + 0][0];
    float* bq1d = &bufd[w * 2 + 1][0];  int* bq1i = &bufi[w * 2 + 1][0];
    int   cnt0 = 0, cnt1 = 0;              // wave-uniform (ballot popcounts)
    float tau0 = INFINITY, tau1 = INFINITY;

    float xqv = xqb[lane];

    for (int t = 0; t < NN / 64; t++) {
        // lane handles point n = t*64+lane; 8 coalesced dwordx4 loads at
        // imm offsets j*1024B from a single per-lane float4 base.
        const float4* pn = (const float4*)(xtb + (size_t)t * 2048) + lane;
        float4 vv[8];
#pragma unroll
        for (int j = 0; j < 8; j++) vv[j] = pn[j * 64];
        float xq_c = xqv;
        v2f c01; c01.x = 0.f; c01.y = 0.f;
#pragma unroll
        for (int j = 0; j < 8; j++) {
            float4 v = vv[j];
            // each half is the ref-exact sequential FMA order f=0..31
            c01 = __builtin_elementwise_fma(qp[4 * j + 0], splat2(v.x), c01);
            c01 = __builtin_elementwise_fma(qp[4 * j + 1], splat2(v.y), c01);
            c01 = __builtin_elementwise_fma(qp[4 * j + 2], splat2(v.z), c01);
            c01 = __builtin_elementwise_fma(qp[4 * j + 3], splat2(v.w), c01);
        }
        if (t + 1 < NN / 64) xqv = xqb[(t + 1) * 64 + lane];

        // ref combine order per half: (ssq + xq) - (c + c)
        v2f d01 = (ssq01 + splat2(xq_c)) - (c01 + c01);
        int n = t * 64 + lane;
        insert_cand(d01.x, n, lane, bq0d, bq0i, cnt0, tau0);
        insert_cand(d01.y, n, lane, bq1d, bq1i, cnt1, tau1);
    }
    // final: compact (lex-sorts survivors) and emit first 32 per query
    wave_compact2(bq0d, bq0i, cnt0, lane);
    wave_compact2(bq1d, bq1i, cnt1, lane);
    int s = s0 + w * 2;
    if (lane < 32) {
        nbr[((size_t)b * SS + s) * KK + lane] = bq0i[lane];
        nbr[((size_t)b * SS + s + 1) * KK + lane] = bq1i[lane];
    }
}

// ---------------------------------------------------------------------------
// K4: features_batch[b,o,s] = max_k h2[b, nbr[b,s,k], o]; block=128, 16 s/block
__global__ __launch_bounds__(128) void maxgather_kernel(const float* __restrict__ h2,
                                                        const int* __restrict__ nbr,
                                                        float* __restrict__ out_feat) {
    __shared__ float fs[128][17];
    int b = blockIdx.x & 7;
    int sg = blockIdx.x >> 3;               // 0..127
    int s0 = sg * 16;
    int tid = threadIdx.x;                  // o = tid (0..127)
    for (int si = 0; si < 16; si++) {
        int s = s0 + si;
        const int* row = nbr + ((size_t)b * SS + s) * KK;
        float m = -INFINITY;
#pragma unroll 4
        for (int k = 0; k < KK; k++) {
            int idx = row[k];
            float v = h2[((size_t)b * NN + idx) * OUTC + tid];
            m = fmaxf(m, v);
        }
        fs[tid][si] = m;
    }
    __syncthreads();
#pragma unroll
    for (int j = 0; j < 16; j++) {
        int flat = j * 128 + tid;
        int fo = flat >> 4, sw = flat & 15;
        out_feat[((size_t)b * OUTC + fo) * SS + s0 + sw] = fs[fo][sw];
    }
}

// ---------------------------------------------------------------------------
extern "C" void kernel_launch(void* const* d_in, const int* in_sizes, int n_in,
                              void* d_out, int out_size, void* d_ws, size_t ws_size,
                              hipStream_t stream) {
    const float* x    = (const float*)d_in[0];
    const int*   sidx = (const int*)d_in[1];
    const float* W1   = (const float*)d_in[2];
    const float* b1   = (const float*)d_in[3];
    const float* W2   = (const float*)d_in[4];
    const float* b2   = (const float*)d_in[5];

    float* out_feat = (float*)d_out;                       // [B,128,S]
    float* out_samp = out_feat + (size_t)BB * OUTC * SS;   // [B,32,S]

    float* h2      = (float*)d_ws;                         // B*N*128 fp32 = 64 MB
    float* sampled = h2 + (size_t)BB * NN * OUTC;          // B*S*F
    float* xsq     = sampled + (size_t)BB * SS * FF;       // B*N
    float* ssq     = xsq + (size_t)BB * NN;                // B*S
    int*   nbr     = (int*)(ssq + (size_t)BB * SS);        // B*S*K
    // xt (16.8 MB) ALIASES the h2 region (64 MB): topk consumes xt strictly
    // before mlp writes h2 (same stream, ordered). No extra workspace.
    float* xt      = h2;

    xsq_kernel<<<dim3(BB * NN / 256), dim3(256), 0, stream>>>(x, xsq);
    gather_kernel<<<dim3(BB * SS / 256), dim3(256), 0, stream>>>(x, sidx, sampled, ssq);
    transpose_kernel<<<dim3(BB * SS / 64), dim3(256), 0, stream>>>(sampled, out_samp);
    transpose_x_kernel<<<dim3(BB * 256), dim3(256), 0, stream>>>(x, xt);
    topk_kernel<<<dim3(BB * SS / 8), dim3(256), 0, stream>>>(xt, xsq, sampled, ssq, nbr);
    mlp_kernel<<<dim3(BB * NN / 64), dim3(256), 0, stream>>>(x, W1, b1, W2, b2, h2);
    maxgather_kernel<<<dim3(BB * SS / 16), dim3(128), 0, stream>>>(h2, nbr, out_feat);
}